// Round 1
// baseline (75.060 us; speedup 1.0000x reference)
//
#include <hip/hip_runtime.h>
#include <hip/hip_bf16.h>
#include <math.h>

#define KCURV  0.1f
#define KK     0.010000001f          // k*k
#define SQRT_K 0.31622776601683794f
#define TWO_SQRT_K 0.6324555320336759f
#define INV_SQRT_K 3.1622776601683795f
#define TD 64   // feature dim D

typedef __bf16  bf16x8  __attribute__((ext_vector_type(8)));
typedef float   f32x4   __attribute__((ext_vector_type(4)));

__device__ __forceinline__ unsigned short f2bf(float f) {
    __hip_bfloat16 h = __float2bfloat16(f);
    return *(unsigned short*)&h;
}

// Single fused kernel: class prep is recomputed per-wave, entirely in
// registers, in exactly the MFMA B-fragment layout. No LDS, no barriers,
// no workspace, one dispatch.
//
// Layout facts (validated in the previous session's kernels):
//   A-frag: A[m=lane&15][k=quad*8+j]  (+32 per step)
//   B-frag: same addressing on class rows
//   C/D:    col=lane&15, row=quad*4+reg
// The 4 quads sharing m16 jointly hold all 64 k of one class row, so the
// per-class reductions (||p||^2, ||a||^2, p.a) finish with shfl_xor(16,32),
// and the per-class scalars land on exactly the lanes (col=m16) that need
// them in the epilogue — no data movement at all.
__global__ __launch_bounds__(256) void fused_mlr_kernel(
    const float* __restrict__ x,
    const float* __restrict__ a_vals,
    const float* __restrict__ p_vals,
    float* __restrict__ out, int B, int C)
{
    const int tid  = threadIdx.x;
    const int w    = tid >> 6;
    const int lane = tid & 63;
    const int m16  = lane & 15;
    const int quad = lane >> 4;
    const int cb   = blockIdx.x * 64;
    const int rb   = blockIdx.y * 64;
    int arow = rb + 16 * w + m16; if (arow >= B) arow = B - 1;

    // ---- issue x loads first (independent of class prep, hides latency) --
    float xv[2][8];
    #pragma unroll
    for (int step = 0; step < 2; ++step) {
        const int ko = quad * 8 + step * 32;
        const float* xr = x + (size_t)arow * TD + ko;
        *(float4*)&xv[step][0] = *(const float4*)xr;
        *(float4*)&xv[step][4] = *(const float4*)(xr + 4);
    }

    // ---- in-register class prep (replaces prep kernel + workspace) -------
    bf16x8 bp[4][2], ba[4][2];
    float x2s[4], pas[4], ans[4], scs[4];
    #pragma unroll
    for (int t = 0; t < 4; ++t) {
        int c = cb + 16 * t + m16; if (c >= C) c = C - 1;   // tail clamp
        const float* pr = p_vals + (size_t)c * TD + quad * 8;
        const float* ar = a_vals + (size_t)c * TD + quad * 8;
        float pv[16], av[16];
        *(float4*)&pv[0]  = *(const float4*)pr;
        *(float4*)&pv[4]  = *(const float4*)(pr + 4);
        *(float4*)&pv[8]  = *(const float4*)(pr + 32);
        *(float4*)&pv[12] = *(const float4*)(pr + 36);
        *(float4*)&av[0]  = *(const float4*)ar;
        *(float4*)&av[4]  = *(const float4*)(ar + 4);
        *(float4*)&av[8]  = *(const float4*)(ar + 32);
        *(float4*)&av[12] = *(const float4*)(ar + 36);

        float s_pp = 0.f, s_aa = 0.f, s_pa = 0.f;
        #pragma unroll
        for (int u = 0; u < 16; ++u) {
            s_pp = fmaf(pv[u], pv[u], s_pp);
            s_aa = fmaf(av[u], av[u], s_aa);
            s_pa = fmaf(pv[u], av[u], s_pa);
        }
        // quads partition k 0..63 -> xor(16)+xor(32) completes row sums
        s_pp += __shfl_xor(s_pp, 16, 64); s_pp += __shfl_xor(s_pp, 32, 64);
        s_aa += __shfl_xor(s_aa, 16, 64); s_aa += __shfl_xor(s_aa, 32, 64);
        s_pa += __shfl_xor(s_pa, 16, 64); s_pa += __shfl_xor(s_pa, 32, 64);

        float pn = sqrtf(s_pp); if (pn < 1e-15f) pn = 1e-15f;
        float arg = SQRT_K * pn;
        // tanh(arg)/arg via fast exp; series guard for tiny arg
        float e2 = __expf(2.0f * arg);
        float th = (e2 - 1.0f) * __builtin_amdgcn_rcpf(e2 + 1.0f);
        float factor = (arg > 1e-4f) ? th * __builtin_amdgcn_rcpf(arg)
                                     : 1.0f - 0.333333333f * arg * arg;
        float p2 = factor * factor * s_pp;      // ||p_poin||^2
        float ca = 1.0f + KCURV * p2;           // a_poin = ca * a
        float anorm = ca * sqrtf(s_aa); if (anorm < 1e-15f) anorm = 1e-15f;
        float lam = 2.0f * __builtin_amdgcn_rcpf(1.0f - KCURV * p2);
        x2s[t] = p2;
        pas[t] = -factor * ca * s_pa;           // sum(mp * a_poin)
        ans[t] = anorm;
        scs[t] = lam * anorm * INV_SQRT_K;

        union { unsigned short u[8]; bf16x8 v; } c0, c1, d0, d1;
        #pragma unroll
        for (int u = 0; u < 8; ++u) {
            c0.u[u] = f2bf(-factor * pv[u]);
            c1.u[u] = f2bf(-factor * pv[8 + u]);
            d0.u[u] = f2bf(ca * av[u]);
            d1.u[u] = f2bf(ca * av[8 + u]);
        }
        bp[t][0] = c0.v; bp[t][1] = c1.v;
        ba[t][0] = d0.v; ba[t][1] = d1.v;
    }

    // ---- y2: exact fp32 row norms, rebroadcast to C-layout rows ----------
    float s = 0.f;
    #pragma unroll
    for (int step = 0; step < 2; ++step)
        #pragma unroll
        for (int u = 0; u < 8; ++u) s = fmaf(xv[step][u], xv[step][u], s);
    s += __shfl_xor(s, 16, 64);
    s += __shfl_xor(s, 32, 64);
    float y2r[4];
    #pragma unroll
    for (int r = 0; r < 4; ++r) y2r[r] = __shfl(s, quad * 4 + r, 64);

    // ---- fp32 -> bf16 A-fragments ----------------------------------------
    bf16x8 af[2];
    #pragma unroll
    for (int step = 0; step < 2; ++step) {
        union { unsigned short u[8]; bf16x8 v; } cv;
        #pragma unroll
        for (int u = 0; u < 8; ++u) cv.u[u] = f2bf(xv[step][u]);
        af[step] = cv.v;
    }

    // ---- dual GEMM: xy = x.mp, xa = x.a_poin -----------------------------
    f32x4 accP[4], accA[4];
    #pragma unroll
    for (int t = 0; t < 4; ++t) {
        accP[t] = (f32x4){0.f, 0.f, 0.f, 0.f};
        accA[t] = (f32x4){0.f, 0.f, 0.f, 0.f};
    }
    #pragma unroll
    for (int step = 0; step < 2; ++step) {
        #pragma unroll
        for (int t = 0; t < 4; ++t) {
            accP[t] = __builtin_amdgcn_mfma_f32_16x16x32_bf16(af[step], bp[t][step], accP[t], 0, 0, 0);
            accA[t] = __builtin_amdgcn_mfma_f32_16x16x32_bf16(af[step], ba[t][step], accA[t], 0, 0, 0);
        }
    }

    // ---- epilogue: per-class scalars already in-lane (col = m16) ---------
    #pragma unroll
    for (int t = 0; t < 4; ++t) {
        const int cl = cb + 16 * t + m16;
        const float x2 = x2s[t], pa = pas[t], an = ans[t], sc = scs[t];
        const float beta = 1.0f - KCURV * x2;
        const float kkx2 = KK * x2;
        #pragma unroll
        for (int r = 0; r < 4; ++r) {
            const int gr = rb + 16 * w + quad * 4 + r;
            const float y2 = y2r[r];
            const float xy = accP[t][r];
            const float xa = accA[t][r];
            float t1    = fmaf(2.0f * KCURV, xy, 1.0f);
            float den   = fmaf(kkx2, y2, t1);                 // mobius denom
            float alpha = fmaf(KCURV, y2, t1);
            float g     = fmaf(alpha, pa, beta * xa);
            float M     = fmaf(alpha * alpha, x2,
                          fmaf(2.0f * alpha * beta, xy, beta * beta * y2));
            // z = 2sqrt(k)·g·den / (an·(den² - k·M))  (single reciprocal)
            float dd    = fmaf(den, den, -KCURV * M);
            float z     = TWO_SQRT_K * g * den * __builtin_amdgcn_rcpf(an * dd);
            float lg    = sc * __logf(z + sqrtf(fmaf(z, z, 1.0f)));   // asinh
            if (cl < C && gr < B) out[(size_t)gr * C + cl] = lg;
        }
    }
}

extern "C" void kernel_launch(void* const* d_in, const int* in_sizes, int n_in,
                              void* d_out, int out_size, void* d_ws, size_t ws_size,
                              hipStream_t stream) {
    const float* x      = (const float*)d_in[0];
    const float* a_vals = (const float*)d_in[1];
    const float* p_vals = (const float*)d_in[2];
    const int B = in_sizes[0] / TD;
    const int C = in_sizes[1] / TD;
    const int rowBlocks = (B + 63) / 64;
    const int clsBlocks = (C + 63) / 64;

    dim3 grid(clsBlocks, rowBlocks);
    fused_mlr_kernel<<<grid, dim3(256), 0, stream>>>(
        x, a_vals, p_vals, (float*)d_out, B, C);
}

// Round 2
// 65.176 us; speedup vs baseline: 1.1516x; 1.1516x over previous
//
#include <hip/hip_runtime.h>
#include <hip/hip_bf16.h>
#include <math.h>

#define KCURV  0.1f
#define KK     0.010000001f          // k*k
#define SQRT_K 0.31622776601683794f
#define TWO_SQRT_K 0.6324555320336759f
#define INV_SQRT_K 3.1622776601683795f
#define TD 64   // feature dim D
#define LDP 72  // LDS row stride in bf16 elems: 144 B -> 2-way max bank alias

typedef __bf16  bf16x8  __attribute__((ext_vector_type(8)));
typedef float   f32x4   __attribute__((ext_vector_type(4)));

__device__ __forceinline__ unsigned short f2bf(float f) {
    __hip_bfloat16 h = __float2bfloat16(f);
    return *(unsigned short*)&h;
}

// Single dispatch, LDS-shared class prep.
//
// Phase 1 (256 threads): each class of the 64-class tile is prepped by 4
// threads (16 k each; shfl_xor(1,2) finishes the row reductions — verified
// pattern from the original prep_kernel). bf16 fragments go to padded LDS
// ([64][72] -> 144 B stride, <=2-way bank alias = free), per-class scalars
// to a 4x64 LDS table. One barrier.
//
// Phase 2 (per wave, no further barriers): b128 fragment reads from LDS,
// x rows read as fp32 + converted in-register, dual MFMA, fused epilogue.
//   A-frag: A[m=lane&15][k=quad*8+j] (+32 per step)
//   C/D:    col=lane&15, row=quad*4+reg   (validated end-to-end earlier)
__global__ __launch_bounds__(256) void fused_mlr_kernel(
    const float* __restrict__ x,
    const float* __restrict__ a_vals,
    const float* __restrict__ p_vals,
    float* __restrict__ out, int B, int C)
{
    __shared__ unsigned short Pl[64 * LDP];
    __shared__ unsigned short Al[64 * LDP];
    __shared__ float scal[4][64];          // x2, pa, an, sc

    const int tid  = threadIdx.x;
    const int w    = tid >> 6;
    const int lane = tid & 63;
    const int m16  = lane & 15;
    const int quad = lane >> 4;
    const int cb   = blockIdx.x * 64;
    const int rb   = blockIdx.y * 64;
    int arow = rb + 16 * w + m16; if (arow >= B) arow = B - 1;

    // ---- issue x loads first (independent of prep, hides latency) -------
    float xv[2][8];
    #pragma unroll
    for (int step = 0; step < 2; ++step) {
        const int ko = quad * 8 + step * 32;
        const float* xr = x + (size_t)arow * TD + ko;
        *(float4*)&xv[step][0] = *(const float4*)xr;
        *(float4*)&xv[step][4] = *(const float4*)(xr + 4);
    }

    // ---- phase 1: cooperative class prep into LDS ------------------------
    {
        const int ci = tid >> 2;           // class within tile, 0..63
        const int q  = tid & 3;            // k-quarter, 16 elems
        int c = cb + ci; if (c >= C) c = C - 1;   // tail clamp (masked on store)
        const float* pr = p_vals + (size_t)c * TD + q * 16;
        const float* ar = a_vals + (size_t)c * TD + q * 16;
        float pv[16], av[16];
        #pragma unroll
        for (int m = 0; m < 4; ++m) {
            *(float4*)&pv[m * 4] = *(const float4*)(pr + m * 4);
            *(float4*)&av[m * 4] = *(const float4*)(ar + m * 4);
        }
        float s_pp = 0.f, s_aa = 0.f, s_pa = 0.f;
        #pragma unroll
        for (int u = 0; u < 16; ++u) {
            s_pp = fmaf(pv[u], pv[u], s_pp);
            s_aa = fmaf(av[u], av[u], s_aa);
            s_pa = fmaf(pv[u], av[u], s_pa);
        }
        s_pp += __shfl_xor(s_pp, 1, 64); s_pp += __shfl_xor(s_pp, 2, 64);
        s_aa += __shfl_xor(s_aa, 1, 64); s_aa += __shfl_xor(s_aa, 2, 64);
        s_pa += __shfl_xor(s_pa, 1, 64); s_pa += __shfl_xor(s_pa, 2, 64);

        float pn = sqrtf(s_pp); if (pn < 1e-15f) pn = 1e-15f;
        float arg = SQRT_K * pn;
        float e2 = __expf(2.0f * arg);
        float th = (e2 - 1.0f) * __builtin_amdgcn_rcpf(e2 + 1.0f);
        float factor = (arg > 1e-4f) ? th * __builtin_amdgcn_rcpf(arg)
                                     : 1.0f - 0.333333333f * arg * arg;
        float p2 = factor * factor * s_pp;      // ||p_poin||^2
        float ca = 1.0f + KCURV * p2;           // a_poin = ca * a
        float anorm = ca * sqrtf(s_aa); if (anorm < 1e-15f) anorm = 1e-15f;
        float lam = 2.0f * __builtin_amdgcn_rcpf(1.0f - KCURV * p2);
        if (q == 0) {
            scal[0][ci] = p2;
            scal[1][ci] = -factor * ca * s_pa;  // sum(mp * a_poin)
            scal[2][ci] = anorm;
            scal[3][ci] = lam * anorm * INV_SQRT_K;
        }
        unsigned short ubp[16], uba[16];
        #pragma unroll
        for (int u = 0; u < 16; ++u) {
            ubp[u] = f2bf(-factor * pv[u]);
            uba[u] = f2bf(ca * av[u]);
        }
        unsigned short* dp = &Pl[ci * LDP + q * 16];
        unsigned short* da = &Al[ci * LDP + q * 16];
        *(ulonglong2*)dp       = *(const ulonglong2*)&ubp[0];
        *(ulonglong2*)(dp + 8) = *(const ulonglong2*)&ubp[8];
        *(ulonglong2*)da       = *(const ulonglong2*)&uba[0];
        *(ulonglong2*)(da + 8) = *(const ulonglong2*)&uba[8];
    }
    __syncthreads();

    // ---- phase 2: fragment reads from LDS --------------------------------
    bf16x8 bp[4][2], ba[4][2];
    #pragma unroll
    for (int step = 0; step < 2; ++step) {
        #pragma unroll
        for (int t = 0; t < 4; ++t) {
            const int off = (16 * t + m16) * LDP + quad * 8 + step * 32;
            bp[t][step] = *(const bf16x8*)&Pl[off];
            ba[t][step] = *(const bf16x8*)&Al[off];
        }
    }

    // y2: exact fp32 row norms, rebroadcast to C-layout rows
    float s = 0.f;
    #pragma unroll
    for (int step = 0; step < 2; ++step)
        #pragma unroll
        for (int u = 0; u < 8; ++u) s = fmaf(xv[step][u], xv[step][u], s);
    s += __shfl_xor(s, 16, 64);
    s += __shfl_xor(s, 32, 64);
    float y2r[4];
    #pragma unroll
    for (int r = 0; r < 4; ++r) y2r[r] = __shfl(s, quad * 4 + r, 64);

    // fp32 -> bf16 A-fragments
    bf16x8 af[2];
    #pragma unroll
    for (int step = 0; step < 2; ++step) {
        union { unsigned short u[8]; bf16x8 v; } cv;
        #pragma unroll
        for (int u = 0; u < 8; ++u) cv.u[u] = f2bf(xv[step][u]);
        af[step] = cv.v;
    }

    // dual GEMM: xy = x.mp, xa = x.a_poin
    f32x4 accP[4], accA[4];
    #pragma unroll
    for (int t = 0; t < 4; ++t) {
        accP[t] = (f32x4){0.f, 0.f, 0.f, 0.f};
        accA[t] = (f32x4){0.f, 0.f, 0.f, 0.f};
    }
    #pragma unroll
    for (int step = 0; step < 2; ++step) {
        #pragma unroll
        for (int t = 0; t < 4; ++t) {
            accP[t] = __builtin_amdgcn_mfma_f32_16x16x32_bf16(af[step], bp[t][step], accP[t], 0, 0, 0);
            accA[t] = __builtin_amdgcn_mfma_f32_16x16x32_bf16(af[step], ba[t][step], accA[t], 0, 0, 0);
        }
    }

    // ---- epilogue: per-class scalars from LDS (broadcast across quads) ---
    #pragma unroll
    for (int t = 0; t < 4; ++t) {
        const int cl = cb + 16 * t + m16;
        const int si = 16 * t + m16;
        const float x2 = scal[0][si], pa = scal[1][si];
        const float an = scal[2][si], sc = scal[3][si];
        const float beta = 1.0f - KCURV * x2;
        const float kkx2 = KK * x2;
        #pragma unroll
        for (int r = 0; r < 4; ++r) {
            const int gr = rb + 16 * w + quad * 4 + r;
            const float y2 = y2r[r];
            const float xy = accP[t][r];
            const float xa = accA[t][r];
            float t1    = fmaf(2.0f * KCURV, xy, 1.0f);
            float den   = fmaf(kkx2, y2, t1);                 // mobius denom
            float alpha = fmaf(KCURV, y2, t1);
            float g     = fmaf(alpha, pa, beta * xa);
            float M     = fmaf(alpha * alpha, x2,
                          fmaf(2.0f * alpha * beta, xy, beta * beta * y2));
            // z = 2sqrt(k)·g·den / (an·(den² - k·M))  (single reciprocal)
            float dd    = fmaf(den, den, -KCURV * M);
            float z     = TWO_SQRT_K * g * den * __builtin_amdgcn_rcpf(an * dd);
            float lg    = sc * __logf(z + sqrtf(fmaf(z, z, 1.0f)));   // asinh
            if (cl < C && gr < B) out[(size_t)gr * C + cl] = lg;
        }
    }
}

extern "C" void kernel_launch(void* const* d_in, const int* in_sizes, int n_in,
                              void* d_out, int out_size, void* d_ws, size_t ws_size,
                              hipStream_t stream) {
    const float* x      = (const float*)d_in[0];
    const float* a_vals = (const float*)d_in[1];
    const float* p_vals = (const float*)d_in[2];
    const int B = in_sizes[0] / TD;
    const int C = in_sizes[1] / TD;
    const int rowBlocks = (B + 63) / 64;
    const int clsBlocks = (C + 63) / 64;

    dim3 grid(clsBlocks, rowBlocks);
    fused_mlr_kernel<<<grid, dim3(256), 0, stream>>>(
        x, a_vals, p_vals, (float*)d_out, B, C);
}

// Round 3
// 64.132 us; speedup vs baseline: 1.1704x; 1.0163x over previous
//
#include <hip/hip_runtime.h>
#include <hip/hip_bf16.h>
#include <math.h>

#define KCURV  0.1f
#define KK     0.010000001f          // k*k
#define SQRT_K 0.31622776601683794f
#define TWO_SQRT_K 0.6324555320336759f
#define INV_SQRT_K 3.1622776601683795f
#define TD 64   // feature dim D
#define LDP 72  // LDS row stride in bf16 elems: 144 B -> 2-way max bank alias

typedef __bf16  bf16x8  __attribute__((ext_vector_type(8)));
typedef float   f32x4   __attribute__((ext_vector_type(4)));

__device__ __forceinline__ unsigned short f2bf(float f) {
    __hip_bfloat16 h = __float2bfloat16(f);
    return *(unsigned short*)&h;
}

// Single dispatch. 512 threads / 8 waves per block, 128 rows x 64 classes
// per block (halves class-prep redundancy vs 64-row blocks; 256 blocks =
// 1/CU, 8 waves/CU — same wave parallelism as before).
//
// Phase 1 (all 512 threads): 8 threads/class x 8 elems; shfl_xor(1,2,4)
// finishes row reductions. bf16 fragments -> padded LDS ([64][72], 144 B
// stride => <=2-way bank alias = free). Class loads are issued BEFORE x
// loads: they feed the barrier-blocking critical path.
//
// Phase 2 (per wave, no further barriers): per-t {b128 frag reads, 4 MFMA,
// fused epilogue, stores} — keeps only 4 B-frags live at a time so the
// scheduler can overlap t+1 LDS reads with t's epilogue VALU.
//   A-frag: A[m=lane&15][k=quad*8+j] (+32 per step)
//   C/D:    col=lane&15, row=quad*4+reg   (validated end-to-end earlier)
__global__ __launch_bounds__(512) void fused_mlr_kernel(
    const float* __restrict__ x,
    const float* __restrict__ a_vals,
    const float* __restrict__ p_vals,
    float* __restrict__ out, int B, int C)
{
    __shared__ unsigned short Pl[64 * LDP];
    __shared__ unsigned short Al[64 * LDP];
    __shared__ float scal[4][64];          // x2, pa, an, sc

    const int tid  = threadIdx.x;
    const int w    = tid >> 6;             // 0..7
    const int lane = tid & 63;
    const int m16  = lane & 15;
    const int quad = lane >> 4;
    const int cb   = blockIdx.x * 64;
    const int rb   = blockIdx.y * 128;
    int arow = rb + 16 * w + m16; if (arow >= B) arow = B - 1;

    // ---- class loads first (critical path: load -> prep -> LDS -> barrier)
    const int ci = tid >> 3;               // class in tile, 0..63
    const int o  = tid & 7;                // k-octet, 8 elems
    int c = cb + ci; if (c >= C) c = C - 1;       // tail clamp (store masked)
    const float* pr = p_vals + (size_t)c * TD + o * 8;
    const float* ar = a_vals + (size_t)c * TD + o * 8;
    float pv[8], av[8];
    *(float4*)&pv[0] = *(const float4*)pr;
    *(float4*)&pv[4] = *(const float4*)(pr + 4);
    *(float4*)&av[0] = *(const float4*)ar;
    *(float4*)&av[4] = *(const float4*)(ar + 4);

    // ---- x loads (independent, consumed after the barrier) ---------------
    float xv[2][8];
    #pragma unroll
    for (int step = 0; step < 2; ++step) {
        const int ko = quad * 8 + step * 32;
        const float* xr = x + (size_t)arow * TD + ko;
        *(float4*)&xv[step][0] = *(const float4*)xr;
        *(float4*)&xv[step][4] = *(const float4*)(xr + 4);
    }

    // ---- phase 1: cooperative class prep into LDS ------------------------
    {
        float s_pp = 0.f, s_aa = 0.f, s_pa = 0.f;
        #pragma unroll
        for (int u = 0; u < 8; ++u) {
            s_pp = fmaf(pv[u], pv[u], s_pp);
            s_aa = fmaf(av[u], av[u], s_aa);
            s_pa = fmaf(pv[u], av[u], s_pa);
        }
        // 8 threads per class -> xor(1,2,4) completes the row sums
        s_pp += __shfl_xor(s_pp, 1, 64); s_aa += __shfl_xor(s_aa, 1, 64);
        s_pa += __shfl_xor(s_pa, 1, 64);
        s_pp += __shfl_xor(s_pp, 2, 64); s_aa += __shfl_xor(s_aa, 2, 64);
        s_pa += __shfl_xor(s_pa, 2, 64);
        s_pp += __shfl_xor(s_pp, 4, 64); s_aa += __shfl_xor(s_aa, 4, 64);
        s_pa += __shfl_xor(s_pa, 4, 64);

        float pn = sqrtf(s_pp); if (pn < 1e-15f) pn = 1e-15f;
        float arg = SQRT_K * pn;
        float e2 = __expf(2.0f * arg);
        float th = (e2 - 1.0f) * __builtin_amdgcn_rcpf(e2 + 1.0f);
        float factor = (arg > 1e-4f) ? th * __builtin_amdgcn_rcpf(arg)
                                     : 1.0f - 0.333333333f * arg * arg;
        float p2 = factor * factor * s_pp;      // ||p_poin||^2
        float ca = 1.0f + KCURV * p2;           // a_poin = ca * a
        float anorm = ca * sqrtf(s_aa); if (anorm < 1e-15f) anorm = 1e-15f;
        float lam = 2.0f * __builtin_amdgcn_rcpf(1.0f - KCURV * p2);
        if (o == 0) {
            scal[0][ci] = p2;
            scal[1][ci] = -factor * ca * s_pa;  // sum(mp * a_poin)
            scal[2][ci] = anorm;
            scal[3][ci] = lam * anorm * INV_SQRT_K;
        }
        union { unsigned short u[8]; bf16x8 v; } cp, da;
        #pragma unroll
        for (int u = 0; u < 8; ++u) {
            cp.u[u] = f2bf(-factor * pv[u]);
            da.u[u] = f2bf(ca * av[u]);
        }
        *(ulonglong2*)&Pl[ci * LDP + o * 8] = *(const ulonglong2*)&cp.u[0];
        *(ulonglong2*)&Al[ci * LDP + o * 8] = *(const ulonglong2*)&da.u[0];
    }
    __syncthreads();

    // ---- y2: exact fp32 row norms, rebroadcast to C-layout rows ----------
    float s = 0.f;
    #pragma unroll
    for (int step = 0; step < 2; ++step)
        #pragma unroll
        for (int u = 0; u < 8; ++u) s = fmaf(xv[step][u], xv[step][u], s);
    s += __shfl_xor(s, 16, 64);
    s += __shfl_xor(s, 32, 64);
    float y2r[4];
    #pragma unroll
    for (int r = 0; r < 4; ++r) y2r[r] = __shfl(s, quad * 4 + r, 64);

    // ---- fp32 -> bf16 A-fragments ----------------------------------------
    bf16x8 af[2];
    #pragma unroll
    for (int step = 0; step < 2; ++step) {
        union { unsigned short u[8]; bf16x8 v; } cv;
        #pragma unroll
        for (int u = 0; u < 8; ++u) cv.u[u] = f2bf(xv[step][u]);
        af[step] = cv.v;
    }

    // ---- per-t: fragment reads, dual MFMA, fused epilogue ----------------
    #pragma unroll
    for (int t = 0; t < 4; ++t) {
        const int off = (16 * t + m16) * LDP + quad * 8;
        bf16x8 bp0 = *(const bf16x8*)&Pl[off];
        bf16x8 ba0 = *(const bf16x8*)&Al[off];
        bf16x8 bp1 = *(const bf16x8*)&Pl[off + 32];
        bf16x8 ba1 = *(const bf16x8*)&Al[off + 32];

        f32x4 accP = (f32x4){0.f, 0.f, 0.f, 0.f};
        f32x4 accA = (f32x4){0.f, 0.f, 0.f, 0.f};
        accP = __builtin_amdgcn_mfma_f32_16x16x32_bf16(af[0], bp0, accP, 0, 0, 0);
        accA = __builtin_amdgcn_mfma_f32_16x16x32_bf16(af[0], ba0, accA, 0, 0, 0);
        accP = __builtin_amdgcn_mfma_f32_16x16x32_bf16(af[1], bp1, accP, 0, 0, 0);
        accA = __builtin_amdgcn_mfma_f32_16x16x32_bf16(af[1], ba1, accA, 0, 0, 0);

        const int cl = cb + 16 * t + m16;
        const int si = 16 * t + m16;
        const float x2 = scal[0][si], pa = scal[1][si];
        const float an = scal[2][si], sc = scal[3][si];
        const float beta = 1.0f - KCURV * x2;
        const float kkx2 = KK * x2;
        #pragma unroll
        for (int r = 0; r < 4; ++r) {
            const int gr = rb + 16 * w + quad * 4 + r;
            const float y2 = y2r[r];
            const float xy = accP[r];
            const float xa = accA[r];
            float t1    = fmaf(2.0f * KCURV, xy, 1.0f);
            float den   = fmaf(kkx2, y2, t1);                 // mobius denom
            float alpha = fmaf(KCURV, y2, t1);
            float g     = fmaf(alpha, pa, beta * xa);
            float M     = fmaf(alpha * alpha, x2,
                          fmaf(2.0f * alpha * beta, xy, beta * beta * y2));
            // z = 2sqrt(k)·g·den / (an·(den² - k·M))  (single reciprocal)
            float dd    = fmaf(den, den, -KCURV * M);
            float z     = TWO_SQRT_K * g * den * __builtin_amdgcn_rcpf(an * dd);
            float lg    = sc * __logf(z + sqrtf(fmaf(z, z, 1.0f)));   // asinh
            if (cl < C && gr < B) out[(size_t)gr * C + cl] = lg;
        }
    }
}

extern "C" void kernel_launch(void* const* d_in, const int* in_sizes, int n_in,
                              void* d_out, int out_size, void* d_ws, size_t ws_size,
                              hipStream_t stream) {
    const float* x      = (const float*)d_in[0];
    const float* a_vals = (const float*)d_in[1];
    const float* p_vals = (const float*)d_in[2];
    const int B = in_sizes[0] / TD;
    const int C = in_sizes[1] / TD;
    const int rowBlocks = (B + 127) / 128;
    const int clsBlocks = (C + 63) / 64;

    dim3 grid(clsBlocks, rowBlocks);
    fused_mlr_kernel<<<grid, dim3(512), 0, stream>>>(
        x, a_vals, p_vals, (float*)d_out, B, C);
}